// Round 16
// baseline (240.889 us; speedup 1.0000x reference)
//
#include <hip/hip_runtime.h>
#include <stdint.h>

typedef __attribute__((ext_vector_type(8))) short short8;
typedef __attribute__((ext_vector_type(4))) short short4v;
typedef __attribute__((ext_vector_type(4))) float f32x4;
typedef uint2 __attribute__((aligned(2))) uint2a2;   // unaligned-safe 8B store

#define MFMA(a,b,c) __builtin_amdgcn_mfma_f32_16x16x32_bf16((a),(b),(c),0,0,0)
#define QSCALE 0.18033688f   /* 0.125 * log2(e): softmax in exp2 domain */
#define VT_LD 584
#define NTOK 577
#define PT_LD 72
#define AS1 __attribute__((address_space(1)))
#define AS3 __attribute__((address_space(3)))

__device__ __forceinline__ unsigned short f2bf(float f) {
    unsigned int u = __float_as_uint(f);
    u += 0x7fffu + ((u >> 16) & 1u);   // RNE
    return (unsigned short)(u >> 16);
}
__device__ __forceinline__ float bf2f(unsigned short u) {
    return __uint_as_float(((unsigned int)u) << 16);
}
__device__ __forceinline__ unsigned int cvt_pk_bf16(float lo, float hi) {
    unsigned int r;
    asm("v_cvt_pk_bf16_f32 %0, %1, %2" : "=v"(r) : "v"(lo), "v"(hi));
    return r;
}

// ---------------- fused prep: x->bf16 (13848 blk) | W_qkv^T (1728 blk) | W_proj^T (576) --
__global__ __launch_bounds__(256) void prep(
    const float* __restrict__ x, unsigned short* __restrict__ xb,
    const float* __restrict__ Wq, unsigned short* __restrict__ Wqt,
    const float* __restrict__ Wp, unsigned short* __restrict__ Wpt)
{
    __shared__ float tile[32][33];
    const int bid = blockIdx.x;
    if (bid < 13848) {                       // cvt: M*C/4 = 3545088 elems of float4
        int i = bid * 256 + threadIdx.x;
        float4 v = ((const float4*)x)[i];
        short4v s;
        s[0] = (short)f2bf(v.x); s[1] = (short)f2bf(v.y);
        s[2] = (short)f2bf(v.z); s[3] = (short)f2bf(v.w);
        ((short4v*)xb)[i] = s;
        return;
    }
    const float* in; unsigned short* out; int R, C, c0, r0;
    if (bid < 13848 + 1728) {                // W_qkv: [768][2304] -> [2304][768]
        int ib = bid - 13848;
        in = Wq; out = Wqt; R = 768; C = 2304;
        c0 = (ib % 72) * 32; r0 = (ib / 72) * 32;
    } else {                                 // W_proj: [768][768] -> [768][768]
        int ib = bid - 15576;
        in = Wp; out = Wpt; R = 768; C = 768;
        c0 = (ib % 24) * 32; r0 = (ib / 24) * 32;
    }
    int lc = threadIdx.x & 31, lr = threadIdx.x >> 5;
    #pragma unroll
    for (int i = 0; i < 4; ++i) {
        int r = lr + i * 8;
        tile[r][lc] = in[(size_t)(r0 + r) * C + c0 + lc];
    }
    __syncthreads();
    #pragma unroll
    for (int i = 0; i < 4; ++i) {
        int r = lr + i * 8;
        out[(size_t)(c0 + r) * R + r0 + lc] = f2bf(tile[lc][r]);
    }
}

// ---- GEMM QKV: 256x256 tile, SINGLE-buffer 2-phase, 8 waves (2Mx4N), 64KB LDS ----
// Staging/read swizzle verbatim from R9 (refcheck-passed, 0 conflicts); sync structure
// from R13's proven winner; packed V^T epilogue re-indexed for acc[8][4].
__global__ __launch_bounds__(512) void gemm256sq(
    const unsigned short* __restrict__ A,
    const unsigned short* __restrict__ Bt,
    const float* __restrict__ bias,
    unsigned short* __restrict__ q_out, unsigned short* __restrict__ k_out,
    unsigned short* __restrict__ vt_out,
    int M, int NB)
{
    __shared__ __align__(16) unsigned short As[256 * 64];   // 32 KB
    __shared__ __align__(16) unsigned short Bs[256 * 64];   // 32 KB

    const int nwg = gridDim.x, orig = blockIdx.x;
    const int qd = nwg >> 3, r8 = nwg & 7;
    const int xcd = orig & 7, j = orig >> 3;
    const int wg = (xcd < r8 ? xcd * (qd + 1) : r8 * (qd + 1) + (xcd - r8) * qd) + j;
    const int bx = wg % NB, by = wg / NB;
    const int m0 = by * 256, n0 = bx * 256;

    const int t = threadIdx.x, lane = t & 63, w = t >> 6;
    const int g = lane >> 4, c = lane & 15;
    const int wr = w >> 2, wcn = w & 3;            // 2M x 4N wave grid
    const int srow = t >> 3;                       // 0..63
    const int csw = (((t & 7) ^ (srow & 7)) * 8);  // pre-swizzled source chunk

    f32x4 acc[8][4] = {};

    for (int k0 = 0; k0 < 768; k0 += 64) {
        #pragma unroll
        for (int i = 0; i < 4; ++i) {              // A: 256 rows in 4 passes
            int row = i * 64 + srow;
            int ra = m0 + row; ra = ra < M ? ra : M - 1;
            __builtin_amdgcn_global_load_lds(
                (const AS1 unsigned int*)&A[(size_t)ra * 768 + k0 + csw],
                (AS3 unsigned int*)&As[i * 4096 + w * 512], 16, 0, 0);
            __builtin_amdgcn_global_load_lds(
                (const AS1 unsigned int*)&Bt[(size_t)(n0 + i * 64 + srow) * 768 + k0 + csw],
                (AS3 unsigned int*)&Bs[i * 4096 + w * 512], 16, 0, 0);
        }
        __syncthreads();
        #pragma unroll
        for (int kk = 0; kk < 2; ++kk) {
            short8 af[8], bfv[4];
            #pragma unroll
            for (int mf = 0; mf < 8; ++mf) {
                int rr = wr * 128 + mf * 16 + c;
                af[mf] = *(const short8*)&As[rr * 64 + (((kk * 4 + g) ^ (c & 7)) * 8)];
            }
            #pragma unroll
            for (int nf = 0; nf < 4; ++nf) {
                int rr = wcn * 64 + nf * 16 + c;
                bfv[nf] = *(const short8*)&Bs[rr * 64 + (((kk * 4 + g) ^ (c & 7)) * 8)];
            }
            __builtin_amdgcn_s_setprio(1);
            #pragma unroll
            for (int mf = 0; mf < 8; ++mf)
            #pragma unroll
            for (int nf = 0; nf < 4; ++nf)
                acc[mf][nf] = MFMA(af[mf], bfv[nf], acc[mf][nf]);
            __builtin_amdgcn_s_setprio(0);
        }
        __syncthreads();
    }

    #pragma unroll
    for (int mf = 0; mf < 8; ++mf)
    #pragma unroll
    for (int nf = 0; nf < 4; ++nf) {
        int n = n0 + wcn * 64 + nf * 16 + c;
        float bv = bias[n];
        int mb = m0 + wr * 128 + mf * 16 + g * 4;     // first of 4 consecutive m
        int which = n / 768;
        int rr = n - which * 768;
        int h = rr >> 6, d = rr & 63;
        if (which == 2) {
            int b0v = mb / 577, tok0 = mb - b0v * 577;
            if (mb + 3 < M && tok0 <= 573) {          // all 4 tokens in one batch
                int bh = b0v * 12 + h;
                uint2 pw;
                pw.x = cvt_pk_bf16(acc[mf][nf][0] + bv, acc[mf][nf][1] + bv);
                pw.y = cvt_pk_bf16(acc[mf][nf][2] + bv, acc[mf][nf][3] + bv);
                *(uint2a2*)&vt_out[((size_t)bh * 64 + d) * VT_LD + tok0] = pw;
            } else {
                #pragma unroll
                for (int e = 0; e < 4; ++e) {
                    int m = mb + e;
                    if (m >= M) continue;
                    int b = m / 577, tok = m - b * 577;
                    vt_out[((size_t)(b * 12 + h) * 64 + d) * VT_LD + tok] =
                        f2bf(acc[mf][nf][e] + bv);
                }
            }
        } else {
            #pragma unroll
            for (int e = 0; e < 4; ++e) {
                int m = mb + e;
                if (m >= M) continue;
                int b = m / 577, tok = m - b * 577;
                int bh = b * 12 + h;
                if (which == 0)
                    q_out[((size_t)bh * 577 + tok) * 64 + d] = f2bf((acc[mf][nf][e] + bv) * QSCALE);
                else
                    k_out[((size_t)bh * 577 + tok) * 64 + d] = f2bf(acc[mf][nf][e] + bv);
            }
        }
    }
}

// ---- GEMM proj: 256x128 tile, 512 thr (4Mx2N), single-buffer 2-phase (R13-proven) ----
__global__ __launch_bounds__(512) void gemm256x128proj(
    const unsigned short* __restrict__ A,
    const unsigned short* __restrict__ Bt,
    const float* __restrict__ bias,
    float* __restrict__ f_out,
    int M, int NB)
{
    __shared__ __align__(16) unsigned short As[256 * 64];
    __shared__ __align__(16) unsigned short Bs[128 * 64];

    const int nwg = gridDim.x, orig = blockIdx.x;
    const int qd = nwg >> 3, r8 = nwg & 7;
    const int xcd = orig & 7, j = orig >> 3;
    const int wg = (xcd < r8 ? xcd * (qd + 1) : r8 * (qd + 1) + (xcd - r8) * qd) + j;
    const int bx = wg % NB, by = wg / NB;
    const int m0 = by * 256, n0 = bx * 128;

    const int t = threadIdx.x, lane = t & 63, w = t >> 6;
    const int g = lane >> 4, c = lane & 15;
    const int wr = w >> 1, wcn = w & 1;            // 4 x 2 wave grid
    const int srow = t >> 3;                       // 0..63
    const int csw = (((t & 7) ^ (srow & 7)) * 8);  // pre-swizzled source chunk

    f32x4 acc[4][4] = {};

    for (int k0 = 0; k0 < 768; k0 += 64) {
        #pragma unroll
        for (int i = 0; i < 4; ++i) {              // A: 256 rows in 4 passes
            int row = i * 64 + srow;
            int ra = m0 + row; ra = ra < M ? ra : M - 1;
            __builtin_amdgcn_global_load_lds(
                (const AS1 unsigned int*)&A[(size_t)ra * 768 + k0 + csw],
                (AS3 unsigned int*)&As[i * 4096 + w * 512], 16, 0, 0);
        }
        #pragma unroll
        for (int i = 0; i < 2; ++i) {              // B: 128 rows in 2 passes
            int row = i * 64 + srow;
            __builtin_amdgcn_global_load_lds(
                (const AS1 unsigned int*)&Bt[(size_t)(n0 + row) * 768 + k0 + csw],
                (AS3 unsigned int*)&Bs[i * 4096 + w * 512], 16, 0, 0);
        }
        __syncthreads();
        #pragma unroll
        for (int kk = 0; kk < 2; ++kk) {
            short8 af[4], bfv[4];
            #pragma unroll
            for (int mf = 0; mf < 4; ++mf) {
                int rr = wr * 64 + mf * 16 + c;
                af[mf] = *(const short8*)&As[rr * 64 + (((kk * 4 + g) ^ (c & 7)) * 8)];
            }
            #pragma unroll
            for (int nf = 0; nf < 4; ++nf) {
                int rr = wcn * 64 + nf * 16 + c;
                bfv[nf] = *(const short8*)&Bs[rr * 64 + (((kk * 4 + g) ^ (c & 7)) * 8)];
            }
            __builtin_amdgcn_s_setprio(1);
            #pragma unroll
            for (int mf = 0; mf < 4; ++mf)
            #pragma unroll
            for (int nf = 0; nf < 4; ++nf)
                acc[mf][nf] = MFMA(af[mf], bfv[nf], acc[mf][nf]);
            __builtin_amdgcn_s_setprio(0);
        }
        __syncthreads();
    }

    #pragma unroll
    for (int mf = 0; mf < 4; ++mf)
    #pragma unroll
    for (int nf = 0; nf < 4; ++nf) {
        int n = n0 + wcn * 64 + nf * 16 + c;
        float bv = bias[n];
        #pragma unroll
        for (int e = 0; e < 4; ++e) {
            int m = m0 + wr * 64 + mf * 16 + g * 4 + e;
            if (m >= M) continue;
            f_out[(size_t)m * 768 + n] = acc[mf][nf][e] + bv;
        }
    }
}

// ---------------- flash attention: LDS-staged K/V (2-phase dbuf), fixed-shift softmax --
__global__ __launch_bounds__(256, 3) void attn_flash(
    const unsigned short* __restrict__ Qg,
    const unsigned short* __restrict__ Kg,
    const unsigned short* __restrict__ Vtg,
    unsigned short* __restrict__ Og)
{
    __shared__ __align__(16) unsigned short KL[2][64][64];
    __shared__ __align__(16) unsigned short VL[2][64][64];
    __shared__ __align__(16) unsigned short pt[4][16][PT_LD];

    const int nwg = gridDim.x, orig = blockIdx.x;
    const int qd = nwg >> 3, jj8 = nwg & 7;
    const int xcd = orig & 7, jj = orig >> 3;
    const int wgid = (xcd < jj8 ? xcd * (qd + 1) : jj8 * (qd + 1) + (xcd - jj8) * qd) + jj;
    const int qt = wgid % 10;
    const int bh = wgid / 10;
    const int b = bh / 12, h = bh - b * 12;
    const int t = threadIdx.x, w = t >> 6, lane = t & 63;
    const int g = lane >> 4, c = lane & 15;
    const int rowi = t >> 3;                        // 0..31
    const int gch = ((t & 7) ^ (rowi & 7)) * 8;     // pre-swizzled source chunk

    const unsigned short* Qh = Qg + (size_t)bh * NTOK * 64;
    const unsigned short* Kh = Kg + (size_t)bh * NTOK * 64;
    const unsigned short* Vh = Vtg + (size_t)bh * 64 * VT_LD;

    const int q = qt * 64 + w * 16 + c;
    const int qc = q < NTOK ? q : NTOK - 1;

    short8 bq0 = *(const short8*)&Qh[(size_t)qc * 64 +      g * 8];
    short8 bq1 = *(const short8*)&Qh[(size_t)qc * 64 + 32 + g * 8];

    auto stage = [&](int buf, int kbase) {
        #pragma unroll
        for (int i = 0; i < 2; ++i) {
            __builtin_amdgcn_global_load_lds(
                (const AS1 unsigned int*)&Kh[(size_t)(kbase + i * 32 + rowi) * 64 + gch],
                (AS3 unsigned int*)(&KL[buf][0][0] + (i * 256 + w * 64) * 8), 16, 0, 0);
            __builtin_amdgcn_global_load_lds(
                (const AS1 unsigned int*)&Vh[(size_t)(i * 32 + rowi) * VT_LD + kbase + gch],
                (AS3 unsigned int*)(&VL[buf][0][0] + (i * 256 + w * 64) * 8), 16, 0, 0);
        }
    };

    f32x4 lsumv = {};
    f32x4 ot[4] = {};

    stage(0, 0);
    __syncthreads();

    int cur = 0;
    for (int kt = 0; kt < 9; ++kt) {
        if (kt < 8) stage(cur ^ 1, (kt + 1) * 64);
        short8 kf0[4], kf1[4];
        #pragma unroll
        for (int f = 0; f < 4; ++f) {
            const unsigned short* kr = &KL[cur][f * 16 + c][0];
            kf0[f] = *(const short8*)&kr[((g    ) ^ (c & 7)) * 8];
            kf1[f] = *(const short8*)&kr[((4 + g) ^ (c & 7)) * 8];
        }
        f32x4 st[4];
        __builtin_amdgcn_s_setprio(1);
        #pragma unroll
        for (int f = 0; f < 4; ++f) {
            f32x4 z = {};
            z = MFMA(kf0[f], bq0, z);
            z = MFMA(kf1[f], bq1, z);
            st[f] = z;
        }
        __builtin_amdgcn_s_setprio(0);
        #pragma unroll
        for (int f = 0; f < 4; ++f) {
            float p0 = exp2f(fminf(st[f][0], 60.f));
            float p1 = exp2f(fminf(st[f][1], 60.f));
            float p2 = exp2f(fminf(st[f][2], 60.f));
            float p3 = exp2f(fminf(st[f][3], 60.f));
            lsumv[0] += p0; lsumv[1] += p1; lsumv[2] += p2; lsumv[3] += p3;
            uint2 pw;
            pw.x = cvt_pk_bf16(p0, p1);
            pw.y = cvt_pk_bf16(p2, p3);
            *(uint2*)&pt[w][c][f * 16 + g * 4] = pw;
        }
        __builtin_amdgcn_s_setprio(1);
        #pragma unroll
        for (int kk = 0; kk < 2; ++kk) {
            short8 bp = *(const short8*)&pt[w][c][kk * 32 + g * 8];
            #pragma unroll
            for (int df = 0; df < 4; ++df) {
                const unsigned short* vr = &VL[cur][df * 16 + c][0];
                short8 av = *(const short8*)&vr[((kk * 4 + g) ^ (c & 7)) * 8];
                ot[df] = MFMA(av, bp, ot[df]);
            }
        }
        __builtin_amdgcn_s_setprio(0);
        __syncthreads();
        cur ^= 1;
    }

    float lsum = (lsumv[0] + lsumv[1]) + (lsumv[2] + lsumv[3]);
    lsum += __shfl_xor(lsum, 16);
    lsum += __shfl_xor(lsum, 32);

    // tail: key 576 (scalar)
    {
        const unsigned short* kp = &Kh[(size_t)576 * 64];
        float dot = 0.f;
        #pragma unroll
        for (int jx = 0; jx < 8; ++jx) {
            dot += bf2f((unsigned short)bq0[jx]) * bf2f(kp[g * 8 + jx]);
            dot += bf2f((unsigned short)bq1[jx]) * bf2f(kp[32 + g * 8 + jx]);
        }
        dot += __shfl_xor(dot, 16);
        dot += __shfl_xor(dot, 32);
        float p = exp2f(fminf(dot, 60.f));
        lsum += p;
        #pragma unroll
        for (int df = 0; df < 4; ++df)
        #pragma unroll
        for (int e = 0; e < 4; ++e)
            ot[df][e] += p * bf2f(Vh[(size_t)(df * 16 + g * 4 + e) * VT_LD + 576]);
    }

    float inv = 1.0f / lsum;
    if (q < NTOK) {
        size_t orow = ((size_t)b * NTOK + q) * 768 + h * 64;
        #pragma unroll
        for (int df = 0; df < 4; ++df) {
            uint2 ov;
            ov.x = cvt_pk_bf16(ot[df][0] * inv, ot[df][1] * inv);
            ov.y = cvt_pk_bf16(ot[df][2] * inv, ot[df][3] * inv);
            *(uint2*)&Og[orow + df * 16 + g * 4] = ov;
        }
    }
}

// ---------------- launch ----------------
extern "C" void kernel_launch(void* const* d_in, const int* in_sizes, int n_in,
                              void* d_out, int out_size, void* d_ws, size_t ws_size,
                              hipStream_t stream) {
    const float* x      = (const float*)d_in[0];
    const float* W_qkv  = (const float*)d_in[1];
    const float* b_qkv  = (const float*)d_in[2];
    const float* W_proj = (const float*)d_in[3];
    const float* b_proj = (const float*)d_in[4];
    float* out = (float*)d_out;

    const int B = 32, N = 577, C = 768, H = 12;
    const int M = B * N;            // 18464

    char* ws = (char*)d_ws;
    size_t off = 0;
    auto alloc = [&](size_t bytes) {
        char* p = ws + off;
        off += (bytes + 255) & ~(size_t)255;
        return p;
    };
    unsigned short* xb    = (unsigned short*)alloc((size_t)M * C * 2);
    unsigned short* wqkvt = (unsigned short*)alloc((size_t)3 * C * C * 2);
    unsigned short* wprjt = (unsigned short*)alloc((size_t)C * C * 2);
    unsigned short* Qb    = (unsigned short*)alloc((size_t)B * H * N * 64 * 2);
    unsigned short* Kb    = (unsigned short*)alloc((size_t)B * H * N * 64 * 2);
    unsigned short* Vtb   = (unsigned short*)alloc((size_t)B * H * 64 * VT_LD * 2);
    unsigned short* attn  = xb;     // x_bf16 dead after QKV GEMM

    // fused prep: cvt (13848) + W_qkv^T (1728) + W_proj^T (576) = 16152 blocks
    prep<<<dim3(16152), 256, 0, stream>>>(x, xb, W_qkv, wqkvt, W_proj, wprjt);

    // QKV: 256x256 single-buffer tiles, 73 x 9 = 657 blocks
    gemm256sq<<<dim3(73 * 9), 512, 0, stream>>>(
        xb, wqkvt, b_qkv, Qb, Kb, Vtb, M, 9);

    attn_flash<<<dim3(3840), 256, 0, stream>>>(Qb, Kb, Vtb, attn);

    // proj: 256x128 tiles, 73 x 6 = 438 blocks (R14-proven)
    gemm256x128proj<<<dim3(73 * 6), 512, 0, stream>>>(
        attn, wprjt, b_proj, out, M, 6);
}

// Round 17
// 204.250 us; speedup vs baseline: 1.1794x; 1.1794x over previous
//
#include <hip/hip_runtime.h>
#include <stdint.h>

typedef __attribute__((ext_vector_type(8))) short short8;
typedef __attribute__((ext_vector_type(4))) short short4v;
typedef __attribute__((ext_vector_type(4))) float f32x4;
typedef uint2 __attribute__((aligned(2))) uint2a2;   // unaligned-safe 8B store

#define MFMA(a,b,c) __builtin_amdgcn_mfma_f32_16x16x32_bf16((a),(b),(c),0,0,0)
#define QSCALE 0.18033688f   /* 0.125 * log2(e): softmax in exp2 domain */
#define VT_LD 584
#define NTOK 577
#define PT_LD 72
#define AS1 __attribute__((address_space(1)))
#define AS3 __attribute__((address_space(3)))

__device__ __forceinline__ unsigned short f2bf(float f) {
    unsigned int u = __float_as_uint(f);
    u += 0x7fffu + ((u >> 16) & 1u);   // RNE
    return (unsigned short)(u >> 16);
}
__device__ __forceinline__ float bf2f(unsigned short u) {
    return __uint_as_float(((unsigned int)u) << 16);
}
__device__ __forceinline__ unsigned int cvt_pk_bf16(float lo, float hi) {
    unsigned int r;
    asm("v_cvt_pk_bf16_f32 %0, %1, %2" : "=v"(r) : "v"(lo), "v"(hi));
    return r;
}

// ---------------- fused prep: x->bf16 (13848 blk) | W_qkv^T (1728 blk) | W_proj^T (576) --
__global__ __launch_bounds__(256) void prep(
    const float* __restrict__ x, unsigned short* __restrict__ xb,
    const float* __restrict__ Wq, unsigned short* __restrict__ Wqt,
    const float* __restrict__ Wp, unsigned short* __restrict__ Wpt)
{
    __shared__ float tile[32][33];
    const int bid = blockIdx.x;
    if (bid < 13848) {                       // cvt: M*C/4 = 3545088 elems of float4
        int i = bid * 256 + threadIdx.x;
        float4 v = ((const float4*)x)[i];
        short4v s;
        s[0] = (short)f2bf(v.x); s[1] = (short)f2bf(v.y);
        s[2] = (short)f2bf(v.z); s[3] = (short)f2bf(v.w);
        ((short4v*)xb)[i] = s;
        return;
    }
    const float* in; unsigned short* out; int R, C, c0, r0;
    if (bid < 13848 + 1728) {                // W_qkv: [768][2304] -> [2304][768]
        int ib = bid - 13848;
        in = Wq; out = Wqt; R = 768; C = 2304;
        c0 = (ib % 72) * 32; r0 = (ib / 72) * 32;
    } else {                                 // W_proj: [768][768] -> [768][768]
        int ib = bid - 15576;
        in = Wp; out = Wpt; R = 768; C = 768;
        c0 = (ib % 24) * 32; r0 = (ib / 24) * 32;
    }
    int lc = threadIdx.x & 31, lr = threadIdx.x >> 5;
    #pragma unroll
    for (int i = 0; i < 4; ++i) {
        int r = lr + i * 8;
        tile[r][lc] = in[(size_t)(r0 + r) * C + c0 + lc];
    }
    __syncthreads();
    #pragma unroll
    for (int i = 0; i < 4; ++i) {
        int r = lr + i * 8;
        out[(size_t)(c0 + r) * R + r0 + lc] = f2bf(tile[lc][r]);
    }
}

// ---- GEMM: 256x128 tile, 512 thr (4Mx2N waves), single-buffer 2-phase (R14-proven) ----
// EPI 0: QKV scatter (packed V^T stores). EPI 1: proj, fp32 out.
template<int EPI>
__global__ __launch_bounds__(512) void gemm256x128(
    const unsigned short* __restrict__ A,
    const unsigned short* __restrict__ Bt,
    const float* __restrict__ bias,
    unsigned short* __restrict__ q_out, unsigned short* __restrict__ k_out,
    unsigned short* __restrict__ vt_out, float* __restrict__ f_out,
    int M, int NB)
{
    __shared__ __align__(16) unsigned short As[256 * 64];
    __shared__ __align__(16) unsigned short Bs[128 * 64];

    const int nwg = gridDim.x, orig = blockIdx.x;
    const int qd = nwg >> 3, r8 = nwg & 7;
    const int xcd = orig & 7, j = orig >> 3;
    const int wg = (xcd < r8 ? xcd * (qd + 1) : r8 * (qd + 1) + (xcd - r8) * qd) + j;
    const int bx = wg % NB, by = wg / NB;
    const int m0 = by * 256, n0 = bx * 128;

    const int t = threadIdx.x, lane = t & 63, w = t >> 6;
    const int g = lane >> 4, c = lane & 15;
    const int wr = w >> 1, wcn = w & 1;            // 4 x 2 wave grid
    const int srow = t >> 3;                       // 0..63
    const int csw = (((t & 7) ^ (srow & 7)) * 8);  // pre-swizzled source chunk

    f32x4 acc[4][4] = {};

    for (int k0 = 0; k0 < 768; k0 += 64) {
        #pragma unroll
        for (int i = 0; i < 4; ++i) {              // A: 256 rows in 4 passes
            int row = i * 64 + srow;
            int ra = m0 + row; ra = ra < M ? ra : M - 1;
            __builtin_amdgcn_global_load_lds(
                (const AS1 unsigned int*)&A[(size_t)ra * 768 + k0 + csw],
                (AS3 unsigned int*)&As[i * 4096 + w * 512], 16, 0, 0);
        }
        #pragma unroll
        for (int i = 0; i < 2; ++i) {              // B: 128 rows in 2 passes
            int row = i * 64 + srow;
            __builtin_amdgcn_global_load_lds(
                (const AS1 unsigned int*)&Bt[(size_t)(n0 + row) * 768 + k0 + csw],
                (AS3 unsigned int*)&Bs[i * 4096 + w * 512], 16, 0, 0);
        }
        __syncthreads();
        #pragma unroll
        for (int kk = 0; kk < 2; ++kk) {
            short8 af[4], bfv[4];
            #pragma unroll
            for (int mf = 0; mf < 4; ++mf) {
                int rr = wr * 64 + mf * 16 + c;
                af[mf] = *(const short8*)&As[rr * 64 + (((kk * 4 + g) ^ (c & 7)) * 8)];
            }
            #pragma unroll
            for (int nf = 0; nf < 4; ++nf) {
                int rr = wcn * 64 + nf * 16 + c;
                bfv[nf] = *(const short8*)&Bs[rr * 64 + (((kk * 4 + g) ^ (c & 7)) * 8)];
            }
            __builtin_amdgcn_s_setprio(1);
            #pragma unroll
            for (int mf = 0; mf < 4; ++mf)
            #pragma unroll
            for (int nf = 0; nf < 4; ++nf)
                acc[mf][nf] = MFMA(af[mf], bfv[nf], acc[mf][nf]);
            __builtin_amdgcn_s_setprio(0);
        }
        __syncthreads();
    }

    #pragma unroll
    for (int mf = 0; mf < 4; ++mf)
    #pragma unroll
    for (int nf = 0; nf < 4; ++nf) {
        int n = n0 + wcn * 64 + nf * 16 + c;
        float bv = bias[n];
        int mb = m0 + wr * 64 + mf * 16 + g * 4;      // first of 4 consecutive m
        if (EPI == 1) {
            #pragma unroll
            for (int e = 0; e < 4; ++e) {
                int m = mb + e;
                if (m >= M) continue;
                f_out[(size_t)m * 768 + n] = acc[mf][nf][e] + bv;
            }
        } else {
            int which = n / 768;
            int rr = n - which * 768;
            int h = rr >> 6, d = rr & 63;
            if (which == 2) {
                int b0v = mb / 577, tok0 = mb - b0v * 577;
                if (mb + 3 < M && tok0 <= 573) {       // all 4 tokens in one batch
                    int bh = b0v * 12 + h;
                    uint2 pw;
                    pw.x = cvt_pk_bf16(acc[mf][nf][0] + bv, acc[mf][nf][1] + bv);
                    pw.y = cvt_pk_bf16(acc[mf][nf][2] + bv, acc[mf][nf][3] + bv);
                    *(uint2a2*)&vt_out[((size_t)bh * 64 + d) * VT_LD + tok0] = pw;
                } else {
                    #pragma unroll
                    for (int e = 0; e < 4; ++e) {
                        int m = mb + e;
                        if (m >= M) continue;
                        int b = m / 577, tok = m - b * 577;
                        vt_out[((size_t)(b * 12 + h) * 64 + d) * VT_LD + tok] =
                            f2bf(acc[mf][nf][e] + bv);
                    }
                }
            } else {
                #pragma unroll
                for (int e = 0; e < 4; ++e) {
                    int m = mb + e;
                    if (m >= M) continue;
                    int b = m / 577, tok = m - b * 577;
                    int bh = b * 12 + h;
                    if (which == 0)
                        q_out[((size_t)bh * 577 + tok) * 64 + d] = f2bf((acc[mf][nf][e] + bv) * QSCALE);
                    else
                        k_out[((size_t)bh * 577 + tok) * 64 + d] = f2bf(acc[mf][nf][e] + bv);
                }
            }
        }
    }
}

// ---------------- flash attention: 128 queries/block (2 q-subtiles share staged K/V) ----
// Q(pre-scaled),K: [B*H][577][64] bf16 ; Vt: [B*H][64][584] bf16 ; O: [B*577][768] bf16
__global__ __launch_bounds__(256, 3) void attn_flash(
    const unsigned short* __restrict__ Qg,
    const unsigned short* __restrict__ Kg,
    const unsigned short* __restrict__ Vtg,
    unsigned short* __restrict__ Og)
{
    __shared__ __align__(16) unsigned short KL[2][64][64];
    __shared__ __align__(16) unsigned short VL[2][64][64];
    __shared__ __align__(16) unsigned short pt[4][16][PT_LD];

    const int nwg = gridDim.x, orig = blockIdx.x;
    const int qd = nwg >> 3, jj8 = nwg & 7;
    const int xcd = orig & 7, jj = orig >> 3;
    const int wgid = (xcd < jj8 ? xcd * (qd + 1) : jj8 * (qd + 1) + (xcd - jj8) * qd) + jj;
    const int qt = wgid % 5;                        // 5 tiles x 128 queries
    const int bh = wgid / 5;
    const int b = bh / 12, h = bh - b * 12;
    const int t = threadIdx.x, w = t >> 6, lane = t & 63;
    const int g = lane >> 4, c = lane & 15;
    const int rowi = t >> 3;                        // 0..31
    const int gch = ((t & 7) ^ (rowi & 7)) * 8;     // pre-swizzled source chunk

    const unsigned short* Qh = Qg + (size_t)bh * NTOK * 64;
    const unsigned short* Kh = Kg + (size_t)bh * NTOK * 64;
    const unsigned short* Vh = Vtg + (size_t)bh * 64 * VT_LD;

    const int q0 = qt * 128 + w * 16 + c;           // lo query (always < 577 for qt<=4)
    const int q1 = q0 + 64;                         // hi query
    const int q0c = q0 < NTOK ? q0 : NTOK - 1;
    const int q1c = q1 < NTOK ? q1 : NTOK - 1;

    short8 bq[2][2];
    bq[0][0] = *(const short8*)&Qh[(size_t)q0c * 64 +      g * 8];
    bq[0][1] = *(const short8*)&Qh[(size_t)q0c * 64 + 32 + g * 8];
    bq[1][0] = *(const short8*)&Qh[(size_t)q1c * 64 +      g * 8];
    bq[1][1] = *(const short8*)&Qh[(size_t)q1c * 64 + 32 + g * 8];

    auto stage = [&](int buf, int kbase) {
        #pragma unroll
        for (int i = 0; i < 2; ++i) {
            __builtin_amdgcn_global_load_lds(
                (const AS1 unsigned int*)&Kh[(size_t)(kbase + i * 32 + rowi) * 64 + gch],
                (AS3 unsigned int*)(&KL[buf][0][0] + (i * 256 + w * 64) * 8), 16, 0, 0);
            __builtin_amdgcn_global_load_lds(
                (const AS1 unsigned int*)&Vh[(size_t)(i * 32 + rowi) * VT_LD + kbase + gch],
                (AS3 unsigned int*)(&VL[buf][0][0] + (i * 256 + w * 64) * 8), 16, 0, 0);
        }
    };

    f32x4 lsumv[2] = {};
    f32x4 ot[2][4] = {};

    stage(0, 0);
    __syncthreads();

    int cur = 0;
    for (int kt = 0; kt < 9; ++kt) {
        if (kt < 8) stage(cur ^ 1, (kt + 1) * 64);
        // K fragments from LDS, shared across both q-subtiles
        short8 kf0[4], kf1[4];
        #pragma unroll
        for (int f = 0; f < 4; ++f) {
            const unsigned short* kr = &KL[cur][f * 16 + c][0];
            kf0[f] = *(const short8*)&kr[((g    ) ^ (c & 7)) * 8];
            kf1[f] = *(const short8*)&kr[((4 + g) ^ (c & 7)) * 8];
        }
        #pragma unroll
        for (int qq = 0; qq < 2; ++qq) {
            f32x4 st[4];
            __builtin_amdgcn_s_setprio(1);
            #pragma unroll
            for (int f = 0; f < 4; ++f) {
                f32x4 z = {};
                z = MFMA(kf0[f], bq[qq][0], z);
                z = MFMA(kf1[f], bq[qq][1], z);
                st[f] = z;
            }
            __builtin_amdgcn_s_setprio(0);
            #pragma unroll
            for (int f = 0; f < 4; ++f) {
                float p0 = exp2f(fminf(st[f][0], 60.f));
                float p1 = exp2f(fminf(st[f][1], 60.f));
                float p2 = exp2f(fminf(st[f][2], 60.f));
                float p3 = exp2f(fminf(st[f][3], 60.f));
                lsumv[qq][0] += p0; lsumv[qq][1] += p1;
                lsumv[qq][2] += p2; lsumv[qq][3] += p3;
                uint2 pw;
                pw.x = cvt_pk_bf16(p0, p1);
                pw.y = cvt_pk_bf16(p2, p3);
                *(uint2*)&pt[w][c][f * 16 + g * 4] = pw;
            }
            __builtin_amdgcn_s_setprio(1);
            #pragma unroll
            for (int kk = 0; kk < 2; ++kk) {
                short8 bp = *(const short8*)&pt[w][c][kk * 32 + g * 8];
                #pragma unroll
                for (int df = 0; df < 4; ++df) {
                    const unsigned short* vr = &VL[cur][df * 16 + c][0];
                    short8 av = *(const short8*)&vr[((kk * 4 + g) ^ (c & 7)) * 8];
                    ot[qq][df] = MFMA(av, bp, ot[qq][df]);
                }
            }
            __builtin_amdgcn_s_setprio(0);
        }
        __syncthreads();
        cur ^= 1;
    }

    float lsum[2];
    #pragma unroll
    for (int qq = 0; qq < 2; ++qq) {
        float s = (lsumv[qq][0] + lsumv[qq][1]) + (lsumv[qq][2] + lsumv[qq][3]);
        s += __shfl_xor(s, 16);
        s += __shfl_xor(s, 32);
        lsum[qq] = s;
    }

    // tail: key 576 (scalar, both q-subtiles)
    {
        const unsigned short* kp = &Kh[(size_t)576 * 64];
        #pragma unroll
        for (int qq = 0; qq < 2; ++qq) {
            float dot = 0.f;
            #pragma unroll
            for (int jx = 0; jx < 8; ++jx) {
                dot += bf2f((unsigned short)bq[qq][0][jx]) * bf2f(kp[g * 8 + jx]);
                dot += bf2f((unsigned short)bq[qq][1][jx]) * bf2f(kp[32 + g * 8 + jx]);
            }
            dot += __shfl_xor(dot, 16);
            dot += __shfl_xor(dot, 32);
            float p = exp2f(fminf(dot, 60.f));
            lsum[qq] += p;
            #pragma unroll
            for (int df = 0; df < 4; ++df)
            #pragma unroll
            for (int e = 0; e < 4; ++e)
                ot[qq][df][e] += p * bf2f(Vh[(size_t)(df * 16 + g * 4 + e) * VT_LD + 576]);
        }
    }

    #pragma unroll
    for (int qq = 0; qq < 2; ++qq) {
        int q = qq == 0 ? q0 : q1;
        if (q < NTOK) {
            float inv = 1.0f / lsum[qq];
            size_t orow = ((size_t)b * NTOK + q) * 768 + h * 64;
            #pragma unroll
            for (int df = 0; df < 4; ++df) {
                uint2 ov;
                ov.x = cvt_pk_bf16(ot[qq][df][0] * inv, ot[qq][df][1] * inv);
                ov.y = cvt_pk_bf16(ot[qq][df][2] * inv, ot[qq][df][3] * inv);
                *(uint2*)&Og[orow + df * 16 + g * 4] = ov;
            }
        }
    }
}

// ---------------- launch ----------------
extern "C" void kernel_launch(void* const* d_in, const int* in_sizes, int n_in,
                              void* d_out, int out_size, void* d_ws, size_t ws_size,
                              hipStream_t stream) {
    const float* x      = (const float*)d_in[0];
    const float* W_qkv  = (const float*)d_in[1];
    const float* b_qkv  = (const float*)d_in[2];
    const float* W_proj = (const float*)d_in[3];
    const float* b_proj = (const float*)d_in[4];
    float* out = (float*)d_out;

    const int B = 32, N = 577, C = 768, H = 12;
    const int M = B * N;            // 18464

    char* ws = (char*)d_ws;
    size_t off = 0;
    auto alloc = [&](size_t bytes) {
        char* p = ws + off;
        off += (bytes + 255) & ~(size_t)255;
        return p;
    };
    unsigned short* xb    = (unsigned short*)alloc((size_t)M * C * 2);
    unsigned short* wqkvt = (unsigned short*)alloc((size_t)3 * C * C * 2);
    unsigned short* wprjt = (unsigned short*)alloc((size_t)C * C * 2);
    unsigned short* Qb    = (unsigned short*)alloc((size_t)B * H * N * 64 * 2);
    unsigned short* Kb    = (unsigned short*)alloc((size_t)B * H * N * 64 * 2);
    unsigned short* Vtb   = (unsigned short*)alloc((size_t)B * H * 64 * VT_LD * 2);
    unsigned short* attn  = xb;     // x_bf16 dead after QKV GEMM

    // fused prep: cvt (13848) + W_qkv^T (1728) + W_proj^T (576) = 16152 blocks
    prep<<<dim3(16152), 256, 0, stream>>>(x, xb, W_qkv, wqkvt, W_proj, wprjt);

    // QKV: 256x128 tiles, 73 x 18 = 1314 blocks (R14-proven)
    gemm256x128<0><<<dim3(73 * 18), 512, 0, stream>>>(
        xb, wqkvt, b_qkv, Qb, Kb, Vtb, nullptr, M, 18);

    // attn: 128 queries/block, 384 heads x 5 tiles = 1920 blocks
    attn_flash<<<dim3(1920), 256, 0, stream>>>(Qb, Kb, Vtb, attn);

    // proj: 256x128 tiles, 73 x 6 = 438 blocks (R14-proven)
    gemm256x128<1><<<dim3(73 * 6), 512, 0, stream>>>(
        attn, wprjt, b_proj, nullptr, nullptr, nullptr, out, M, 6);
}